// Round 3
// baseline (615.413 us; speedup 1.0000x reference)
//
#include <hip/hip_runtime.h>
#include <hip/hip_bf16.h>

#define DHID 128
#define NH 12
#define KDIM 1536   // NH * DHID

typedef __attribute__((ext_vector_type(8))) short short8;
typedef __attribute__((ext_vector_type(4))) float f32x4;

static __device__ __forceinline__ unsigned short f2bf(float f) {
  __hip_bfloat16 h = __float2bfloat16(f);
  return __builtin_bit_cast(unsigned short, h);
}

// ---------------- sort (counting sort of edges by dst) ----------------

__global__ void hist_k(const int* __restrict__ dstp, int* __restrict__ cnt, int e0, int et) {
  int e = blockIdx.x * blockDim.x + threadIdx.x;
  if (e >= et) return;
  int d = (e < e0) ? dstp[e] : (e - e0);   // self-loop edges appended at the end
  atomicAdd(&cnt[d], 1);
}

// cnt and cursor may alias (in-place): each element is read before rewrite.
__global__ void scan_k(const int* __restrict__ cnt, int* __restrict__ row_start,
                       int* __restrict__ cursor, int n, int total) {
  __shared__ int part[1024];
  int t = threadIdx.x;
  const int CH = (n + 1023) >> 10;
  int base = t * CH;
  int s = 0;
  for (int j = 0; j < CH; ++j) { int i = base + j; if (i < n) s += cnt[i]; }
  part[t] = s;
  __syncthreads();
  for (int off = 1; off < 1024; off <<= 1) {
    int v = (t >= off) ? part[t - off] : 0;
    __syncthreads();
    part[t] += v;
    __syncthreads();
  }
  int run = (t == 0) ? 0 : part[t - 1];
  for (int j = 0; j < CH; ++j) {
    int i = base + j;
    if (i < n) {
      int c = cnt[i];              // read BEFORE cursor write (may alias)
      row_start[i] = run;
      cursor[i] = run;
      run += c;
    }
  }
  if (t == 0) row_start[n] = total;
}

__global__ void scatter_k(const int* __restrict__ srcp, const int* __restrict__ dstp,
                          int* __restrict__ cursor, int* __restrict__ srcs,
                          int* __restrict__ dsts, int e0, int et) {
  int e = blockIdx.x * blockDim.x + threadIdx.x;
  if (e >= et) return;
  int s = (e < e0) ? srcp[e] : (e - e0);
  int d = (e < e0) ? dstp[e] : (e - e0);
  int pos = atomicAdd(&cursor[d], 1);
  srcs[pos] = s;
  dsts[pos] = d;
}

// ---------------- per-node u = x . Wu[h] ----------------

__global__ void u_k(const float* __restrict__ x, const float* __restrict__ Wu,
                    float* __restrict__ u, int n) {
  int wid = (blockIdx.x * blockDim.x + threadIdx.x) >> 6;
  if (wid >= n) return;
  int lane = threadIdx.x & 63;
  float2 xv = *(const float2*)(x + (long)wid * DHID + 2 * lane);
  #pragma unroll
  for (int h = 0; h < NH; ++h) {
    float2 wv = *(const float2*)(Wu + h * DHID + 2 * lane);
    float p = xv.x * wv.x + xv.y * wv.y;
    p += __shfl_xor(p, 1);  p += __shfl_xor(p, 2);  p += __shfl_xor(p, 4);
    p += __shfl_xor(p, 8);  p += __shfl_xor(p, 16); p += __shfl_xor(p, 32);
    if (lane == 0) u[wid * NH + h] = p;
  }
}

// ---------------- per-edge attention (thread per edge, dst-sorted order) ----------------
// attS[j][h] = softmax_h(u[dst]-u[src]+c) / deg(dst)

__global__ void att_k(const float* __restrict__ u, const float* __restrict__ cvec,
                      const int* __restrict__ srcs, const int* __restrict__ dsts,
                      const int* __restrict__ row_start, float* __restrict__ attS, int et) {
  int j = blockIdx.x * blockDim.x + threadIdx.x;
  if (j >= et) return;
  int s = srcs[j], d = dsts[j];
  const float4* ud = (const float4*)(u + (long)d * NH);
  const float4* us = (const float4*)(u + (long)s * NH);
  const float4* cp = (const float4*)cvec;
  float w[NH];
  #pragma unroll
  for (int q = 0; q < 3; ++q) {
    float4 a = ud[q], b = us[q], c = cp[q];
    w[4*q+0] = a.x - b.x + c.x;
    w[4*q+1] = a.y - b.y + c.y;
    w[4*q+2] = a.z - b.z + c.z;
    w[4*q+3] = a.w - b.w + c.w;
  }
  float m = w[0];
  #pragma unroll
  for (int h = 1; h < NH; ++h) m = fmaxf(m, w[h]);
  float ssum = 0.f;
  #pragma unroll
  for (int h = 0; h < NH; ++h) { w[h] = __expf(w[h] - m); ssum += w[h]; }
  float deg = (float)(row_start[d + 1] - row_start[d]);
  float inv = 1.f / (ssum * deg);
  float4* op = (float4*)(attS + (long)j * NH);
  #pragma unroll
  for (int q = 0; q < 3; ++q) {
    float4 v;
    v.x = w[4*q+0] * inv; v.y = w[4*q+1] * inv;
    v.z = w[4*q+2] * inv; v.w = w[4*q+3] * inv;
    op[q] = v;
  }
}

// ---------------- edge aggregation: A[n,h,:] = sum_j attS[j,h] * x[srcs[j]] ----------------

__global__ void edge_k(const float* __restrict__ x, const float* __restrict__ attS,
                       const int* __restrict__ srcs, const int* __restrict__ row_start,
                       unsigned short* __restrict__ A, int n) {
  int wid = __builtin_amdgcn_readfirstlane((int)((blockIdx.x * blockDim.x + threadIdx.x) >> 6));
  if (wid >= n) return;
  int lane = threadIdx.x & 63;
  float acc[NH][2];
  #pragma unroll
  for (int h = 0; h < NH; ++h) { acc[h][0] = 0.f; acc[h][1] = 0.f; }
  int beg = row_start[wid], end = row_start[wid + 1];
  int j = beg;
  for (; j + 1 < end; j += 2) {
    int s0 = srcs[j], s1 = srcs[j + 1];
    float2 xv0 = *(const float2*)(x + (long)s0 * DHID + 2 * lane);
    float2 xv1 = *(const float2*)(x + (long)s1 * DHID + 2 * lane);
    const float4* a0p = (const float4*)(attS + (long)j * NH);
    float4 a00 = a0p[0], a01 = a0p[1], a02 = a0p[2];
    float4 a10 = a0p[3], a11 = a0p[4], a12 = a0p[5];
    float av0[NH], av1[NH];
    av0[0]=a00.x; av0[1]=a00.y; av0[2]=a00.z;  av0[3]=a00.w;
    av0[4]=a01.x; av0[5]=a01.y; av0[6]=a01.z;  av0[7]=a01.w;
    av0[8]=a02.x; av0[9]=a02.y; av0[10]=a02.z; av0[11]=a02.w;
    av1[0]=a10.x; av1[1]=a10.y; av1[2]=a10.z;  av1[3]=a10.w;
    av1[4]=a11.x; av1[5]=a11.y; av1[6]=a11.z;  av1[7]=a11.w;
    av1[8]=a12.x; av1[9]=a12.y; av1[10]=a12.z; av1[11]=a12.w;
    #pragma unroll
    for (int h = 0; h < NH; ++h) {
      acc[h][0] += av0[h] * xv0.x + av1[h] * xv1.x;
      acc[h][1] += av0[h] * xv0.y + av1[h] * xv1.y;
    }
  }
  if (j < end) {
    int s0 = srcs[j];
    float2 xv0 = *(const float2*)(x + (long)s0 * DHID + 2 * lane);
    const float4* a0p = (const float4*)(attS + (long)j * NH);
    float4 a00 = a0p[0], a01 = a0p[1], a02 = a0p[2];
    float av0[NH];
    av0[0]=a00.x; av0[1]=a00.y; av0[2]=a00.z;  av0[3]=a00.w;
    av0[4]=a01.x; av0[5]=a01.y; av0[6]=a01.z;  av0[7]=a01.w;
    av0[8]=a02.x; av0[9]=a02.y; av0[10]=a02.z; av0[11]=a02.w;
    #pragma unroll
    for (int h = 0; h < NH; ++h) {
      acc[h][0] += av0[h] * xv0.x;
      acc[h][1] += av0[h] * xv0.y;
    }
  }
  unsigned* Ap = (unsigned*)(A + (long)wid * KDIM);
  #pragma unroll
  for (int h = 0; h < NH; ++h) {
    unsigned pv = (unsigned)f2bf(acc[h][0]) | ((unsigned)f2bf(acc[h][1]) << 16);
    Ap[h * (DHID / 2) + lane] = pv;
  }
}

// ---------------- weight repack: Wcat[c][h*128+k] = Wlin[h*128+c][k], bf16 ----------------

__global__ void prep_wcat_k(const float* __restrict__ Wlin, unsigned short* __restrict__ Wcat) {
  int t = blockIdx.x * blockDim.x + threadIdx.x;  // 128*1536 total
  int c = t / KDIM, f = t - c * KDIM;
  int h = f >> 7, k = f & (DHID - 1);
  Wcat[t] = f2bf(Wlin[((h << 7) + c) * DHID + k]);
}

// ---------------- GEMM: out[n,c] = (A[n,:] . Wcat[c,:]) + bias[c] ----------------
// 16 rows per block, 4 waves each covering 32 cols; 1250 blocks -> ~5 waves/SIMD.

__global__ __launch_bounds__(256) void gemm_k(
    const unsigned short* __restrict__ A, const unsigned short* __restrict__ B,
    const float* __restrict__ bias,
    float* __restrict__ out, float* __restrict__ bnpart,
    int M, int relu, int dobn) {
  int w = threadIdx.x >> 6, lane = threadIdx.x & 63;
  int lr = lane & 15, lq = lane >> 4;
  int m0 = blockIdx.x * 16, n0 = w * 32;
  if (m0 >= M) return;
  f32x4 acc[2];
  acc[0] = (f32x4){0.f, 0.f, 0.f, 0.f};
  acc[1] = (f32x4){0.f, 0.f, 0.f, 0.f};
  const short* Ap = (const short*)A;
  const short* Bp = (const short*)B;
  long arow  = (long)(m0 + lr) * KDIM + lq * 8;
  long brow0 = (long)(n0 + lr) * KDIM + lq * 8;
  long brow1 = (long)(n0 + 16 + lr) * KDIM + lq * 8;
  #pragma unroll 4
  for (int kk = 0; kk < KDIM; kk += 32) {
    short8 av  = *(const short8*)(Ap + arow + kk);
    short8 bv0 = *(const short8*)(Bp + brow0 + kk);
    short8 bv1 = *(const short8*)(Bp + brow1 + kk);
    acc[0] = __builtin_amdgcn_mfma_f32_16x16x32_bf16(av, bv0, acc[0], 0, 0, 0);
    acc[1] = __builtin_amdgcn_mfma_f32_16x16x32_bf16(av, bv1, acc[1], 0, 0, 0);
  }
  // epilogue: + bias, optional relu, optional BN partial stats (32-slice spread)
  #pragma unroll
  for (int nf = 0; nf < 2; ++nf) {
    int c = n0 + nf * 16 + lr;
    float bc = bias[c];
    float s_part = 0.f, q_part = 0.f;
    int rowb = m0 + lq * 4;
    #pragma unroll
    for (int r = 0; r < 4; ++r) {
      int row = rowb + r;
      if (row < M) {
        float v = acc[nf][r] + bc;
        if (relu) v = fmaxf(v, 0.f);
        out[(long)row * DHID + c] = v;
        s_part += v; q_part += v * v;
      }
    }
    if (dobn) {
      s_part += __shfl_xor(s_part, 16); s_part += __shfl_xor(s_part, 32);
      q_part += __shfl_xor(q_part, 16); q_part += __shfl_xor(q_part, 32);
      if (lq == 0) {
        float* bp = bnpart + (blockIdx.x & 31) * 256;
        atomicAdd(&bp[c], s_part);
        atomicAdd(&bp[128 + c], q_part);
      }
    }
  }
}

// ---------------- BatchNorm finalize + apply (in place) ----------------

__global__ void bnfin_k(const float* __restrict__ bnpart,
                        const float* __restrict__ g, const float* __restrict__ b,
                        float* __restrict__ sc, float* __restrict__ sh, float invn) {
  int c = threadIdx.x;
  float s = 0.f, q = 0.f;
  #pragma unroll
  for (int i = 0; i < 32; ++i) {
    s += bnpart[i * 256 + c];
    q += bnpart[i * 256 + 128 + c];
  }
  float m = s * invn;
  float v = q * invn - m * m;
  float rs = rsqrtf(v + 1e-5f);
  float sg = g[c] * rs;
  sc[c] = sg;
  sh[c] = b[c] - m * sg;
}

__global__ void bnapply_k(float* __restrict__ buf, const float* __restrict__ sc,
                          const float* __restrict__ sh, int nvec) {
  int i = blockIdx.x * blockDim.x + threadIdx.x;
  if (i >= nvec) return;
  long idx = (long)i * 4;
  int c = (int)(idx & (DHID - 1));
  float4 v = *(const float4*)(buf + idx);
  v.x = v.x * sc[c]     + sh[c];
  v.y = v.y * sc[c + 1] + sh[c + 1];
  v.z = v.z * sc[c + 2] + sh[c + 2];
  v.w = v.w * sc[c + 3] + sh[c + 3];
  *(float4*)(buf + idx) = v;
}

// ---------------- launch ----------------

extern "C" void kernel_launch(void* const* d_in, const int* in_sizes, int n_in,
                              void* d_out, int out_size, void* d_ws, size_t ws_size,
                              hipStream_t stream) {
  const float* x = (const float*)d_in[0];
  const int* ei = (const int*)d_in[1];
  const int N = in_sizes[0] / DHID;
  const int E0 = in_sizes[1] / 2;
  const int ET = E0 + N;
  const int* srcp = ei;
  const int* dstp = ei + E0;
  const float* Wlin[3] = {(const float*)d_in[2], (const float*)d_in[6], (const float*)d_in[10]};
  const float* Wu[3]   = {(const float*)d_in[3], (const float*)d_in[7], (const float*)d_in[11]};
  const float* cc[3]   = {(const float*)d_in[4], (const float*)d_in[8], (const float*)d_in[12]};
  const float* bb[3]   = {(const float*)d_in[5], (const float*)d_in[9], (const float*)d_in[13]};
  const float* bng[2]  = {(const float*)d_in[14], (const float*)d_in[16]};
  const float* bnb[2]  = {(const float*)d_in[15], (const float*)d_in[17]};

  const int MPAD = ((N + 63) / 64) * 64;

  // carve workspace
  size_t o = 0;
  char* base = (char*)d_ws;
  auto carve = [&](size_t bytes) -> char* {
    char* p = base + o;
    o += (bytes + 255) & ~(size_t)255;
    return p;
  };
  int* row_start = (int*)carve((size_t)(N + 1) * 4);
  int* cursor    = (int*)carve((size_t)N * 4);       // doubles as histogram
  int* srcs      = (int*)carve((size_t)ET * 4);
  int* dsts      = (int*)carve((size_t)ET * 4);
  float* u       = (float*)carve((size_t)N * NH * 4);
  float* bnpart  = (float*)carve((size_t)32 * 256 * 4);
  float* bnsc    = (float*)carve((size_t)DHID * 4);
  float* bnsh    = (float*)carve((size_t)DHID * 4);
  unsigned short* Wcat = (unsigned short*)carve((size_t)DHID * KDIM * 2);
  float* attS    = (float*)carve((size_t)ET * NH * 4);
  float* hA      = (float*)carve((size_t)N * DHID * 4);
  unsigned short* A = (unsigned short*)carve((size_t)MPAD * KDIM * 2);
  (void)ws_size; (void)n_in; (void)out_size;

  const int EB = (ET + 255) / 256;
  const int NW = (N + 3) / 4;       // 4 waves (nodes) per 256-thread block
  const int MB16 = (N + 15) / 16;
  const int AV = (N * DHID / 4 + 255) / 256;

  // sort edges by dst (once; dst list is layer-invariant)
  hipMemsetAsync(cursor, 0, (size_t)N * 4, stream);
  hist_k<<<EB, 256, 0, stream>>>(dstp, cursor, E0, ET);
  scan_k<<<1, 1024, 0, stream>>>(cursor, row_start, cursor, N, ET);
  scatter_k<<<EB, 256, 0, stream>>>(srcp, dstp, cursor, srcs, dsts, E0, ET);

  const float* hin = x;
  for (int li = 0; li < 3; ++li) {
    const bool last = (li == 2);
    u_k<<<NW, 256, 0, stream>>>(hin, Wu[li], u, N);
    att_k<<<EB, 256, 0, stream>>>(u, cc[li], srcs, dsts, row_start, attS, ET);
    edge_k<<<NW, 256, 0, stream>>>(hin, attS, srcs, row_start, A, N);
    prep_wcat_k<<<(DHID * KDIM) / 256, 256, 0, stream>>>(Wlin[li], Wcat);
    if (!last) hipMemsetAsync(bnpart, 0, (size_t)32 * 256 * 4, stream);
    float* outp = last ? (float*)d_out : hA;
    gemm_k<<<MB16, 256, 0, stream>>>(A, Wcat, bb[li], outp, bnpart,
                                     N, last ? 0 : 1, last ? 0 : 1);
    if (!last) {
      bnfin_k<<<1, DHID, 0, stream>>>(bnpart, bng[li], bnb[li], bnsc, bnsh, 1.f / (float)N);
      bnapply_k<<<AV, 256, 0, stream>>>(hA, bnsc, bnsh, N * DHID / 4);
      hin = hA;
    }
  }
}